// Round 4
// baseline (291.424 us; speedup 1.0000x reference)
//
#include <hip/hip_runtime.h>
#include <hip/hip_bf16.h>
#include <stdint.h>

// NT-Xent loss, B=4096, D=256, T=0.5, eps=1e-8.
// loss_r = log(sum_{c!=r} exp(2*dot(zn_r,zn_c))) - 2*dot(zin_r, zjn_r); out = mean.
// zn_s = zn * sqrt(2*log2e) stored bf16 -> MFMA acc = 2*log2e*dot -> exp2(acc) direct.
// Diagonal accumulated unconditionally; subtracted in k_loss via exp2(diag), where
// diag = sum(zn_s_bf16^2) is the exact bf16 self-dot.

#define BROWS 4096
#define DIM   256
#define N2    8192

typedef __attribute__((ext_vector_type(4))) float          f32x4;
typedef __attribute__((ext_vector_type(8))) short          s16x8;
typedef __attribute__((ext_vector_type(4))) unsigned short u16x4;

#define S_EXP  1.6986436597467051f   /* sqrt(2*log2(e)) */
#define LN2    0.6931471805599453f

__device__ inline unsigned short f2bf(float f) {
    uint32_t b = __float_as_uint(f);
    b += 0x7fffu + ((b >> 16) & 1u);   // RNE
    return (unsigned short)(b >> 16);
}
__device__ inline float bf2f(unsigned short u) {
    return __uint_as_float(((uint32_t)u) << 16);
}

__device__ inline void gload_lds16(const void* g, void* l) {
    __builtin_amdgcn_global_load_lds(
        (const __attribute__((address_space(1))) uint32_t*)g,
        (__attribute__((address_space(3))) uint32_t*)l, 16, 0, 0);
}

__device__ inline float wave_reduce(float v) {
    #pragma unroll
    for (int m = 1; m < 64; m <<= 1) v += __shfl_xor(v, m);
    return v;
}

// ---- K1: fused normalize (both views) + positive-pair exponent + diag self-dot ----
// Also zeroes the completion counter used by k_loss's last-block finish.
__global__ __launch_bounds__(256) void k_norm_pos(const float* __restrict__ zi,
                                                  const float* __restrict__ zj,
                                                  unsigned short* __restrict__ zn,
                                                  float* __restrict__ diag,
                                                  float* __restrict__ posv,
                                                  unsigned int* __restrict__ counter) {
    if (blockIdx.x == 0 && threadIdx.x == 0) *counter = 0u;
    int i    = blockIdx.x * 4 + (threadIdx.x >> 6);
    int lane = threadIdx.x & 63;
    f32x4 a = *(const f32x4*)(zi + (size_t)i * DIM + lane * 4);
    f32x4 b = *(const f32x4*)(zj + (size_t)i * DIM + lane * 4);
    float ssa = a[0]*a[0] + a[1]*a[1] + a[2]*a[2] + a[3]*a[3];
    float ssb = b[0]*b[0] + b[1]*b[1] + b[2]*b[2] + b[3]*b[3];
    float dab = a[0]*b[0] + a[1]*b[1] + a[2]*b[2] + a[3]*b[3];
    ssa = wave_reduce(ssa);
    ssb = wave_reduce(ssb);
    dab = wave_reduce(dab);
    float na = 1.0f / fmaxf(sqrtf(ssa), 1e-8f);
    float nb = 1.0f / fmaxf(sqrtf(ssb), 1e-8f);
    if (lane == 0) posv[i] = 2.0f * dab * na * nb;   // natural-log exponent of pos pair

    float sa = na * S_EXP, sb = nb * S_EXP;
    u16x4 oa, ob;
    float da = 0.0f, db = 0.0f;
    #pragma unroll
    for (int k = 0; k < 4; ++k) {
        unsigned short ua = f2bf(a[k] * sa);
        unsigned short ub = f2bf(b[k] * sb);
        oa[k] = ua; ob[k] = ub;
        float fa = bf2f(ua), fb = bf2f(ub);
        da += fa * fa; db += fb * fb;
    }
    *(u16x4*)(zn + (size_t)i * DIM + lane * 4)           = oa;
    *(u16x4*)(zn + (size_t)(i + BROWS) * DIM + lane * 4) = ob;
    da = wave_reduce(da);
    db = wave_reduce(db);
    if (lane == 0) { diag[i] = da; diag[i + BROWS] = db; }
}

// ---- K2: fused sim GEMM + exp2 + row-sum (diagonal NOT masked) ----
// 256 thr = 4 waves; 256 rows x 256 cols per block; grid = 32*32 = 1024 -> 4 blocks/CU.
// Wave owns 64 rows (4 row-tiles of 16), A-frags pinned (128 VGPR, K=256).
// Single 32 KB LDS buffer (keeps 4 blocks/CU resident; inter-block overlap hides
// the per-step stage drain). LDS layout: byte = kc*4096 + g*1024 + col*16
//   holds zn[colbase + s*64 + col][kc*32 + g*8 .. +8]
__global__ __launch_bounds__(256, 4) void k_simsum(const unsigned short* __restrict__ zn,
                                                   float* __restrict__ partial) {
    __shared__ unsigned short lds[64 * DIM];   // 32 KB
    int bid = blockIdx.x;
    int rb = bid & 31;        // 32 row-blocks of 256
    int cc = bid >> 5;        // 32 col-chunks of 256
    int rowbase = rb * 256;
    int colbase = cc * 256;
    int tid = threadIdx.x, lane = tid & 63, w = tid >> 6;   // w in 0..3
    int cl = lane & 15, g = lane >> 4;

    // A fragments: lane holds zn[rowbase + w*64 + rt*16 + cl][kc*32 + g*8 .. +8]
    s16x8 afrag[4][8];
    #pragma unroll
    for (int rt = 0; rt < 4; ++rt) {
        int row = rowbase + w * 64 + rt * 16 + cl;
        const unsigned short* ap = zn + (size_t)row * DIM + g * 8;
        #pragma unroll
        for (int kc = 0; kc < 8; ++kc)
            afrag[rt][kc] = *(const s16x8*)(ap + kc * 32);
    }

    float pp[4][4];
    #pragma unroll
    for (int rt = 0; rt < 4; ++rt)
        #pragma unroll
        for (int r = 0; r < 4; ++r) pp[rt][r] = 0.0f;

    for (int s = 0; s < 4; ++s) {
        __syncthreads();   // previous step's LDS reads done
        {
            int crow = colbase + s * 64 + lane;
            const unsigned short* gsrc = zn + (size_t)crow * DIM;
            #pragma unroll
            for (int i = 0; i < 8; ++i)
                gload_lds16(gsrc + i * 32 + w * 8, (char*)lds + i * 4096 + w * 1024);
        }
        __syncthreads();   // staging complete

        #pragma unroll
        for (int ct = 0; ct < 4; ++ct) {
            f32x4 acc[4];
            #pragma unroll
            for (int rt = 0; rt < 4; ++rt) acc[rt] = (f32x4){0.f, 0.f, 0.f, 0.f};
            #pragma unroll
            for (int kc = 0; kc < 8; ++kc) {
                s16x8 bfrag = *(const s16x8*)((const char*)lds + kc * 4096 + g * 1024 +
                                              (ct * 16 + cl) * 16);
                #pragma unroll
                for (int rt = 0; rt < 4; ++rt)
                    acc[rt] = __builtin_amdgcn_mfma_f32_16x16x32_bf16(
                                  afrag[rt][kc], bfrag, acc[rt], 0, 0, 0);
            }
            #pragma unroll
            for (int rt = 0; rt < 4; ++rt)
                #pragma unroll
                for (int r = 0; r < 4; ++r)
                    pp[rt][r] += __builtin_amdgcn_exp2f(acc[rt][r]);
        }
    }

    // reduce across the 16 col-lanes (cl) within each g-group
    #pragma unroll
    for (int rt = 0; rt < 4; ++rt) {
        #pragma unroll
        for (int r = 0; r < 4; ++r) {
            float v = pp[rt][r];
            v += __shfl_xor(v, 1);
            v += __shfl_xor(v, 2);
            v += __shfl_xor(v, 4);
            v += __shfl_xor(v, 8);
            if (cl == 0)
                partial[(size_t)cc * N2 + rowbase + w * 64 + rt * 16 + g * 4 + r] = v;
        }
    }
}

// ---- K3: per-row loss over 32 blocks; last block finishes the mean ----
__global__ __launch_bounds__(256) void k_loss(const float* __restrict__ partial,
                                              const float* __restrict__ diag,
                                              const float* __restrict__ posv,
                                              float* __restrict__ blocksum,
                                              unsigned int* __restrict__ counter,
                                              float* __restrict__ out) {
    int row = blockIdx.x * 256 + threadIdx.x;
    float sum = 0.0f;
    #pragma unroll
    for (int c = 0; c < 32; ++c) sum += partial[(size_t)c * N2 + row];
    sum -= __builtin_amdgcn_exp2f(diag[row]);           // remove diagonal term
    float lr = __builtin_amdgcn_logf(sum) * LN2 - posv[row & (BROWS - 1)];
    lr = wave_reduce(lr);
    __shared__ float red[4];
    if ((threadIdx.x & 63) == 0) red[threadIdx.x >> 6] = lr;
    __syncthreads();
    if (threadIdx.x == 0) {
        blocksum[blockIdx.x] = red[0] + red[1] + red[2] + red[3];
        __threadfence();                                  // publish blocksum
        unsigned int old = atomicAdd(counter, 1u);        // device-scope
        if (old == 31u) {                                 // last block finishes
            __threadfence();                              // acquire
            volatile const float* bs = blocksum;
            float t = 0.0f;
            for (int i = 0; i < 32; ++i) t += bs[i];
            out[0] = t * (1.0f / N2);
        }
    }
}

extern "C" void kernel_launch(void* const* d_in, const int* in_sizes, int n_in,
                              void* d_out, int out_size, void* d_ws, size_t ws_size,
                              hipStream_t stream) {
    const float* zi = (const float*)d_in[0];
    const float* zj = (const float*)d_in[1];
    float* out = (float*)d_out;

    char* ws = (char*)d_ws;
    unsigned short* zn    = (unsigned short*)ws;                       // 4 MB
    float* diag           = (float*)(ws + (4u << 20));                 // 32 KB
    float* posv           = (float*)(ws + (4u << 20) + (32u << 10));   // 16 KB
    float* blocksum       = (float*)(ws + (4u << 20) + (48u << 10));   // 128 B
    unsigned int* counter = (unsigned int*)(ws + (4u << 20) + (52u << 10));
    float* partial        = (float*)(ws + (4u << 20) + (64u << 10));   // 1 MB

    k_norm_pos<<<BROWS / 4, 256, 0, stream>>>(zi, zj, zn, diag, posv, counter);
    k_simsum<<<1024, 256, 0, stream>>>(zn, partial);
    k_loss<<<32, 256, 0, stream>>>(partial, diag, posv, blocksum, counter, out);
}

// Round 5
// 85.798 us; speedup vs baseline: 3.3966x; 3.3966x over previous
//
#include <hip/hip_runtime.h>
#include <hip/hip_bf16.h>
#include <stdint.h>

// NT-Xent loss, B=4096, D=256, T=0.5, eps=1e-8.
// loss_r = log(sum_{c!=r} exp(2*dot(zn_r,zn_c))) - 2*dot(zin_r, zjn_r); out = mean.
// zn_s = zn * sqrt(2*log2e) stored bf16 -> MFMA acc = 2*log2e*dot -> exp2(acc) direct.
// Diagonal accumulated unconditionally; subtracted in k_loss via exp2(diag), where
// diag = sum(zn_s_bf16^2) is the exact bf16 self-dot.
//
// LESSON (R2/R4): __launch_bounds__ arg2 > 2 halves the unified VGPR budget and
// spills afrag -> 6x regression. Natural allocation is 128 VGPR; hardware already
// schedules 4 waves/SIMD with that. Occupancy comes from grid size (1024 = 4
// blocks/CU), NOT from launch_bounds.

#define BROWS 4096
#define DIM   256
#define N2    8192

typedef __attribute__((ext_vector_type(4))) float          f32x4;
typedef __attribute__((ext_vector_type(8))) short          s16x8;
typedef __attribute__((ext_vector_type(4))) unsigned short u16x4;

#define S_EXP  1.6986436597467051f   /* sqrt(2*log2(e)) */
#define LN2    0.6931471805599453f

__device__ inline unsigned short f2bf(float f) {
    uint32_t b = __float_as_uint(f);
    b += 0x7fffu + ((b >> 16) & 1u);   // RNE
    return (unsigned short)(b >> 16);
}
__device__ inline float bf2f(unsigned short u) {
    return __uint_as_float(((uint32_t)u) << 16);
}

__device__ inline void gload_lds16(const void* g, void* l) {
    __builtin_amdgcn_global_load_lds(
        (const __attribute__((address_space(1))) uint32_t*)g,
        (__attribute__((address_space(3))) uint32_t*)l, 16, 0, 0);
}

__device__ inline float wave_reduce(float v) {
    #pragma unroll
    for (int m = 1; m < 64; m <<= 1) v += __shfl_xor(v, m);
    return v;
}

// ---- K1: fused normalize (both views) + positive-pair exponent + diag self-dot ----
// Also zeroes the completion counter used by k_loss's last-block finish.
__global__ __launch_bounds__(256) void k_norm_pos(const float* __restrict__ zi,
                                                  const float* __restrict__ zj,
                                                  unsigned short* __restrict__ zn,
                                                  float* __restrict__ diag,
                                                  float* __restrict__ posv,
                                                  unsigned int* __restrict__ counter) {
    if (blockIdx.x == 0 && threadIdx.x == 0) *counter = 0u;
    int i    = blockIdx.x * 4 + (threadIdx.x >> 6);
    int lane = threadIdx.x & 63;
    f32x4 a = *(const f32x4*)(zi + (size_t)i * DIM + lane * 4);
    f32x4 b = *(const f32x4*)(zj + (size_t)i * DIM + lane * 4);
    float ssa = a[0]*a[0] + a[1]*a[1] + a[2]*a[2] + a[3]*a[3];
    float ssb = b[0]*b[0] + b[1]*b[1] + b[2]*b[2] + b[3]*b[3];
    float dab = a[0]*b[0] + a[1]*b[1] + a[2]*b[2] + a[3]*b[3];
    ssa = wave_reduce(ssa);
    ssb = wave_reduce(ssb);
    dab = wave_reduce(dab);
    float na = 1.0f / fmaxf(sqrtf(ssa), 1e-8f);
    float nb = 1.0f / fmaxf(sqrtf(ssb), 1e-8f);
    if (lane == 0) posv[i] = 2.0f * dab * na * nb;   // natural-log exponent of pos pair

    float sa = na * S_EXP, sb = nb * S_EXP;
    u16x4 oa, ob;
    float da = 0.0f, db = 0.0f;
    #pragma unroll
    for (int k = 0; k < 4; ++k) {
        unsigned short ua = f2bf(a[k] * sa);
        unsigned short ub = f2bf(b[k] * sb);
        oa[k] = ua; ob[k] = ub;
        float fa = bf2f(ua), fb = bf2f(ub);
        da += fa * fa; db += fb * fb;
    }
    *(u16x4*)(zn + (size_t)i * DIM + lane * 4)           = oa;
    *(u16x4*)(zn + (size_t)(i + BROWS) * DIM + lane * 4) = ob;
    da = wave_reduce(da);
    db = wave_reduce(db);
    if (lane == 0) { diag[i] = da; diag[i + BROWS] = db; }
}

// ---- K2: fused sim GEMM + exp2 + row-sum (diagonal NOT masked) ----
// 256 thr = 4 waves; 256 rows x 256 cols per block; grid = 32*32 = 1024 -> 4 blocks/CU.
// Wave owns 64 rows (4 row-tiles of 16), A-frags pinned (128 VGPR natural, K=256).
// Single 32 KB LDS buffer; 4 resident blocks/CU hide the per-step stage drain.
// LDS layout: byte = kc*4096 + g*1024 + col*16
//   holds zn[colbase + s*64 + col][kc*32 + g*8 .. +8]
__global__ __launch_bounds__(256, 2) void k_simsum(const unsigned short* __restrict__ zn,
                                                   float* __restrict__ partial) {
    __shared__ unsigned short lds[64 * DIM];   // 32 KB
    int bid = blockIdx.x;
    int rb = bid & 31;        // 32 row-blocks of 256
    int cc = bid >> 5;        // 32 col-chunks of 256
    int rowbase = rb * 256;
    int colbase = cc * 256;
    int tid = threadIdx.x, lane = tid & 63, w = tid >> 6;   // w in 0..3
    int cl = lane & 15, g = lane >> 4;

    // A fragments: lane holds zn[rowbase + w*64 + rt*16 + cl][kc*32 + g*8 .. +8]
    s16x8 afrag[4][8];
    #pragma unroll
    for (int rt = 0; rt < 4; ++rt) {
        int row = rowbase + w * 64 + rt * 16 + cl;
        const unsigned short* ap = zn + (size_t)row * DIM + g * 8;
        #pragma unroll
        for (int kc = 0; kc < 8; ++kc)
            afrag[rt][kc] = *(const s16x8*)(ap + kc * 32);
    }

    float pp[4][4];
    #pragma unroll
    for (int rt = 0; rt < 4; ++rt)
        #pragma unroll
        for (int r = 0; r < 4; ++r) pp[rt][r] = 0.0f;

    for (int s = 0; s < 4; ++s) {
        __syncthreads();   // previous step's LDS reads done
        {
            int crow = colbase + s * 64 + lane;
            const unsigned short* gsrc = zn + (size_t)crow * DIM;
            #pragma unroll
            for (int i = 0; i < 8; ++i)
                gload_lds16(gsrc + i * 32 + w * 8, (char*)lds + i * 4096 + w * 1024);
        }
        __syncthreads();   // staging complete

        #pragma unroll
        for (int ct = 0; ct < 4; ++ct) {
            f32x4 acc[4];
            #pragma unroll
            for (int rt = 0; rt < 4; ++rt) acc[rt] = (f32x4){0.f, 0.f, 0.f, 0.f};
            #pragma unroll
            for (int kc = 0; kc < 8; ++kc) {
                s16x8 bfrag = *(const s16x8*)((const char*)lds + kc * 4096 + g * 1024 +
                                              (ct * 16 + cl) * 16);
                #pragma unroll
                for (int rt = 0; rt < 4; ++rt)
                    acc[rt] = __builtin_amdgcn_mfma_f32_16x16x32_bf16(
                                  afrag[rt][kc], bfrag, acc[rt], 0, 0, 0);
            }
            #pragma unroll
            for (int rt = 0; rt < 4; ++rt)
                #pragma unroll
                for (int r = 0; r < 4; ++r)
                    pp[rt][r] += __builtin_amdgcn_exp2f(acc[rt][r]);
        }
    }

    // reduce across the 16 col-lanes (cl) within each g-group
    #pragma unroll
    for (int rt = 0; rt < 4; ++rt) {
        #pragma unroll
        for (int r = 0; r < 4; ++r) {
            float v = pp[rt][r];
            v += __shfl_xor(v, 1);
            v += __shfl_xor(v, 2);
            v += __shfl_xor(v, 4);
            v += __shfl_xor(v, 8);
            if (cl == 0)
                partial[(size_t)cc * N2 + rowbase + w * 64 + rt * 16 + g * 4 + r] = v;
        }
    }
}

// ---- K3: per-row loss over 32 blocks; last block finishes the mean ----
__global__ __launch_bounds__(256) void k_loss(const float* __restrict__ partial,
                                              const float* __restrict__ diag,
                                              const float* __restrict__ posv,
                                              float* __restrict__ blocksum,
                                              unsigned int* __restrict__ counter,
                                              float* __restrict__ out) {
    int row = blockIdx.x * 256 + threadIdx.x;
    float sum = 0.0f;
    #pragma unroll
    for (int c = 0; c < 32; ++c) sum += partial[(size_t)c * N2 + row];
    sum -= __builtin_amdgcn_exp2f(diag[row]);           // remove diagonal term
    float lr = __builtin_amdgcn_logf(sum) * LN2 - posv[row & (BROWS - 1)];
    lr = wave_reduce(lr);
    __shared__ float red[4];
    if ((threadIdx.x & 63) == 0) red[threadIdx.x >> 6] = lr;
    __syncthreads();
    if (threadIdx.x == 0) {
        blocksum[blockIdx.x] = red[0] + red[1] + red[2] + red[3];
        __threadfence();                                  // publish blocksum
        unsigned int old = atomicAdd(counter, 1u);        // device-scope
        if (old == 31u) {                                 // last block finishes
            __threadfence();                              // acquire
            volatile const float* bs = blocksum;
            float t = 0.0f;
            for (int i = 0; i < 32; ++i) t += bs[i];
            out[0] = t * (1.0f / N2);
        }
    }
}

extern "C" void kernel_launch(void* const* d_in, const int* in_sizes, int n_in,
                              void* d_out, int out_size, void* d_ws, size_t ws_size,
                              hipStream_t stream) {
    const float* zi = (const float*)d_in[0];
    const float* zj = (const float*)d_in[1];
    float* out = (float*)d_out;

    char* ws = (char*)d_ws;
    unsigned short* zn    = (unsigned short*)ws;                       // 4 MB
    float* diag           = (float*)(ws + (4u << 20));                 // 32 KB
    float* posv           = (float*)(ws + (4u << 20) + (32u << 10));   // 16 KB
    float* blocksum       = (float*)(ws + (4u << 20) + (48u << 10));   // 128 B
    unsigned int* counter = (unsigned int*)(ws + (4u << 20) + (52u << 10));
    float* partial        = (float*)(ws + (4u << 20) + (64u << 10));   // 1 MB

    k_norm_pos<<<BROWS / 4, 256, 0, stream>>>(zi, zj, zn, diag, posv, counter);
    k_simsum<<<1024, 256, 0, stream>>>(zn, partial);
    k_loss<<<32, 256, 0, stream>>>(partial, diag, posv, blocksum, counter, out);
}

// Round 6
// 85.690 us; speedup vs baseline: 3.4009x; 1.0013x over previous
//
#include <hip/hip_runtime.h>
#include <hip/hip_bf16.h>
#include <stdint.h>

// NT-Xent loss, B=4096, D=256, T=0.5, eps=1e-8.
// loss_r = log(sum_{c!=r} exp(2*dot(zn_r,zn_c))) - 2*dot(zin_r, zjn_r); out = mean.
// zn_s = zn * sqrt(2*log2e) stored bf16 -> MFMA acc = 2*log2e*dot -> exp2(acc) direct.
// Diagonal accumulated unconditionally; subtracted in k_loss via exp2(diag), where
// diag = sum(zn_s_bf16^2) is the exact bf16 self-dot.
//
// R6: NO LDS in the GEMM. R1-R5 showed the B-tile LDS path is port-bound
// (8 waves x 32 ds_read_b128 x 12cyc = 3072 cyc/CU/step vs 1242 cyc MFMA).
// zn is 4 MB == one XCD L2; B-fragments are loaded straight from global with
// the same line-coalesced gather as the A-fragments, two tiles in flight.

#define BROWS 4096
#define DIM   256
#define N2    8192

typedef __attribute__((ext_vector_type(4))) float          f32x4;
typedef __attribute__((ext_vector_type(8))) short          s16x8;
typedef __attribute__((ext_vector_type(4))) unsigned short u16x4;

#define S_EXP  1.6986436597467051f   /* sqrt(2*log2(e)) */
#define LN2    0.6931471805599453f

__device__ inline unsigned short f2bf(float f) {
    uint32_t b = __float_as_uint(f);
    b += 0x7fffu + ((b >> 16) & 1u);   // RNE
    return (unsigned short)(b >> 16);
}
__device__ inline float bf2f(unsigned short u) {
    return __uint_as_float(((uint32_t)u) << 16);
}

__device__ inline float wave_reduce(float v) {
    #pragma unroll
    for (int m = 1; m < 64; m <<= 1) v += __shfl_xor(v, m);
    return v;
}

// ---- K1: fused normalize (both views) + positive-pair exponent + diag self-dot ----
// Also zeroes the completion counter used by k_loss's last-block finish.
__global__ __launch_bounds__(256) void k_norm_pos(const float* __restrict__ zi,
                                                  const float* __restrict__ zj,
                                                  unsigned short* __restrict__ zn,
                                                  float* __restrict__ diag,
                                                  float* __restrict__ posv,
                                                  unsigned int* __restrict__ counter) {
    if (blockIdx.x == 0 && threadIdx.x == 0) *counter = 0u;
    int i    = blockIdx.x * 4 + (threadIdx.x >> 6);
    int lane = threadIdx.x & 63;
    f32x4 a = *(const f32x4*)(zi + (size_t)i * DIM + lane * 4);
    f32x4 b = *(const f32x4*)(zj + (size_t)i * DIM + lane * 4);
    float ssa = a[0]*a[0] + a[1]*a[1] + a[2]*a[2] + a[3]*a[3];
    float ssb = b[0]*b[0] + b[1]*b[1] + b[2]*b[2] + b[3]*b[3];
    float dab = a[0]*b[0] + a[1]*b[1] + a[2]*b[2] + a[3]*b[3];
    ssa = wave_reduce(ssa);
    ssb = wave_reduce(ssb);
    dab = wave_reduce(dab);
    float na = 1.0f / fmaxf(sqrtf(ssa), 1e-8f);
    float nb = 1.0f / fmaxf(sqrtf(ssb), 1e-8f);
    if (lane == 0) posv[i] = 2.0f * dab * na * nb;   // natural-log exponent of pos pair

    float sa = na * S_EXP, sb = nb * S_EXP;
    u16x4 oa, ob;
    float da = 0.0f, db = 0.0f;
    #pragma unroll
    for (int k = 0; k < 4; ++k) {
        unsigned short ua = f2bf(a[k] * sa);
        unsigned short ub = f2bf(b[k] * sb);
        oa[k] = ua; ob[k] = ub;
        float fa = bf2f(ua), fb = bf2f(ub);
        da += fa * fa; db += fb * fb;
    }
    *(u16x4*)(zn + (size_t)i * DIM + lane * 4)           = oa;
    *(u16x4*)(zn + (size_t)(i + BROWS) * DIM + lane * 4) = ob;
    da = wave_reduce(da);
    db = wave_reduce(db);
    if (lane == 0) { diag[i] = da; diag[i + BROWS] = db; }
}

// ---- K2: fused sim GEMM + exp2 + row-sum, NO LDS ----
// 256 thr = 4 waves; block = 256 rows x 512 cols; grid = 32*16 = 512.
// Wave owns 64 rows (afrag[4][8] pinned, 64 VGPRs). B-fragments loaded directly
// from global (L2-resident zn), two 16-col tiles in flight (bufA/bufB).
__global__ __launch_bounds__(256, 2) void k_simsum(const unsigned short* __restrict__ zn,
                                                   float* __restrict__ partial) {
    int bid = blockIdx.x;
    int rb = bid & 31;        // 32 row-blocks of 256
    int cc = bid >> 5;        // 16 col-chunks of 512
    int rowbase = rb * 256;
    int colbase = cc * 512;
    int tid = threadIdx.x, lane = tid & 63, w = tid >> 6;   // w in 0..3
    int cl = lane & 15, g = lane >> 4;

    // A fragments: lane holds zn[rowbase + w*64 + rt*16 + cl][kc*32 + g*8 .. +8]
    s16x8 afrag[4][8];
    #pragma unroll
    for (int rt = 0; rt < 4; ++rt) {
        int row = rowbase + w * 64 + rt * 16 + cl;
        const unsigned short* ap = zn + (size_t)row * DIM + g * 8;
        #pragma unroll
        for (int kc = 0; kc < 8; ++kc)
            afrag[rt][kc] = *(const s16x8*)(ap + kc * 32);
    }

    float pp[4][4];
    #pragma unroll
    for (int rt = 0; rt < 4; ++rt)
        #pragma unroll
        for (int r = 0; r < 4; ++r) pp[rt][r] = 0.0f;

    // B-fragment gather base for this lane: col = colbase + ct*16 + cl, bytes k g*8..
    const unsigned short* bp = zn + (size_t)(colbase + cl) * DIM + g * 8;

    s16x8 bufA[8], bufB[8];

    #define LOADB(buf, ct)                                            \
        {                                                             \
            const unsigned short* p_ = bp + (size_t)(ct) * 16 * DIM;  \
            _Pragma("unroll")                                         \
            for (int kc = 0; kc < 8; ++kc)                            \
                buf[kc] = *(const s16x8*)(p_ + kc * 32);              \
        }

    #define COMPUTE(buf, ct)                                                      \
        {                                                                         \
            f32x4 acc[4];                                                         \
            _Pragma("unroll")                                                     \
            for (int rt = 0; rt < 4; ++rt) acc[rt] = (f32x4){0.f, 0.f, 0.f, 0.f}; \
            _Pragma("unroll")                                                     \
            for (int kc = 0; kc < 8; ++kc) {                                      \
                _Pragma("unroll")                                                 \
                for (int rt = 0; rt < 4; ++rt)                                    \
                    acc[rt] = __builtin_amdgcn_mfma_f32_16x16x32_bf16(            \
                                  afrag[rt][kc], buf[kc], acc[rt], 0, 0, 0);      \
            }                                                                     \
            _Pragma("unroll")                                                     \
            for (int rt = 0; rt < 4; ++rt)                                        \
                _Pragma("unroll")                                                 \
                for (int r = 0; r < 4; ++r)                                       \
                    pp[rt][r] += __builtin_amdgcn_exp2f(acc[rt][r]);              \
        }

    LOADB(bufA, 0)
    #pragma unroll 1
    for (int t = 0; t < 32; t += 2) {
        if (t + 1 < 32) LOADB(bufB, t + 1)
        COMPUTE(bufA, t)
        if (t + 2 < 32) LOADB(bufA, t + 2)
        if (t + 1 < 32) COMPUTE(bufB, t + 1)
    }
    #undef LOADB
    #undef COMPUTE

    // reduce across the 16 col-lanes (cl) within each g-group
    #pragma unroll
    for (int rt = 0; rt < 4; ++rt) {
        #pragma unroll
        for (int r = 0; r < 4; ++r) {
            float v = pp[rt][r];
            v += __shfl_xor(v, 1);
            v += __shfl_xor(v, 2);
            v += __shfl_xor(v, 4);
            v += __shfl_xor(v, 8);
            if (cl == 0)
                partial[(size_t)cc * N2 + rowbase + w * 64 + rt * 16 + g * 4 + r] = v;
        }
    }
}

// ---- K3: per-row loss over 32 blocks; last block finishes the mean ----
__global__ __launch_bounds__(256) void k_loss(const float* __restrict__ partial,
                                              const float* __restrict__ diag,
                                              const float* __restrict__ posv,
                                              float* __restrict__ blocksum,
                                              unsigned int* __restrict__ counter,
                                              float* __restrict__ out) {
    int row = blockIdx.x * 256 + threadIdx.x;
    float sum = 0.0f;
    #pragma unroll
    for (int c = 0; c < 16; ++c) sum += partial[(size_t)c * N2 + row];
    sum -= __builtin_amdgcn_exp2f(diag[row]);           // remove diagonal term
    float lr = __builtin_amdgcn_logf(sum) * LN2 - posv[row & (BROWS - 1)];
    lr = wave_reduce(lr);
    __shared__ float red[4];
    if ((threadIdx.x & 63) == 0) red[threadIdx.x >> 6] = lr;
    __syncthreads();
    if (threadIdx.x == 0) {
        blocksum[blockIdx.x] = red[0] + red[1] + red[2] + red[3];
        __threadfence();                                  // publish blocksum
        unsigned int old = atomicAdd(counter, 1u);        // device-scope
        if (old == 31u) {                                 // last block finishes
            __threadfence();                              // acquire
            volatile const float* bs = blocksum;
            float t = 0.0f;
            for (int i = 0; i < 32; ++i) t += bs[i];
            out[0] = t * (1.0f / N2);
        }
    }
}

extern "C" void kernel_launch(void* const* d_in, const int* in_sizes, int n_in,
                              void* d_out, int out_size, void* d_ws, size_t ws_size,
                              hipStream_t stream) {
    const float* zi = (const float*)d_in[0];
    const float* zj = (const float*)d_in[1];
    float* out = (float*)d_out;

    char* ws = (char*)d_ws;
    unsigned short* zn    = (unsigned short*)ws;                       // 4 MB
    float* diag           = (float*)(ws + (4u << 20));                 // 32 KB
    float* posv           = (float*)(ws + (4u << 20) + (32u << 10));   // 16 KB
    float* blocksum       = (float*)(ws + (4u << 20) + (48u << 10));   // 128 B
    unsigned int* counter = (unsigned int*)(ws + (4u << 20) + (52u << 10));
    float* partial        = (float*)(ws + (4u << 20) + (64u << 10));   // 512 KB

    k_norm_pos<<<BROWS / 4, 256, 0, stream>>>(zi, zj, zn, diag, posv, counter);
    k_simsum<<<512, 256, 0, stream>>>(zn, partial);
    k_loss<<<32, 256, 0, stream>>>(partial, diag, posv, blocksum, counter, out);
}